// Round 6
// baseline (141.521 us; speedup 1.0000x reference)
//
#include <hip/hip_runtime.h>
#include <math.h>

#define DIMX 256
#define NFEAT 32
#define BATCH 512
#define HEADS 8
#define DHEAD 32
#define KNN 17
#define QKV_W 768
#define SCALE_F 0.17677669529663687f

typedef unsigned int uint;
typedef unsigned short ushort_t;
typedef __attribute__((ext_vector_type(8))) short short8_t;   // 8 bf16 (4 VGPRs)
typedef __attribute__((ext_vector_type(4))) float float4_t;   // MFMA acc

__device__ inline float bf_lo(uint u) { return __uint_as_float(u << 16); }
__device__ inline float bf_hi(uint u) { return __uint_as_float(u & 0xffff0000u); }
__device__ inline ushort_t f2bf(float f) {
  uint u = __float_as_uint(f);
  return (ushort_t)((u + 0x7fffu + ((u >> 16) & 1u)) >> 16);
}

// ---------------- Stage A: reprs = mean(x,axis=1) @ W_repr + b_repr; normalize ----------------
__global__ void repr_kernel(const float* __restrict__ x, const float* __restrict__ W_repr,
                            const float* __restrict__ b_repr, float* __restrict__ normed) {
  int b = blockIdx.x, t = threadIdx.x;
  __shared__ float mean_s[DIMX];
  __shared__ float red[DIMX];
  float s = 0.f;
#pragma unroll
  for (int n = 0; n < NFEAT; ++n) s += x[(size_t)(b*NFEAT+n)*DIMX + t];
  mean_s[t] = s * (1.0f/NFEAT);
  __syncthreads();
  float acc = b_repr[t];
  for (int d = 0; d < DIMX; ++d) acc += mean_s[d] * W_repr[d*DIMX + t];
  red[t] = acc*acc;
  __syncthreads();
  for (int off = 128; off > 0; off >>= 1) {
    if (t < off) red[t] += red[t+off];
    __syncthreads();
  }
  normed[b*DIMX + t] = acc / sqrtf(red[0]);
}

// ---------------- Stage B: sims (vectorized) + top-17 via per-wave extraction -----------------
// Block = one row i. Dot phase: float4 streams (L1/L2-resident). Top-k: each wave extracts its
// local top-17 of 128 values with shfl_xor butterflies (no barriers), wave 0 merges 68 cands.
__global__ __launch_bounds__(256, 4) void simtopk_kernel(const float* __restrict__ normed,
                                                         int* __restrict__ knn) {
  int i = blockIdx.x, t = threadIdx.x;
  int l = t & 63, w = t >> 6;
  __shared__ float myrow[DIMX];
  __shared__ float sims[BATCH];
  __shared__ float candv[4][KNN];
  __shared__ int   candi[4][KNN];
  myrow[t] = normed[(size_t)i*DIMX + t];
  __syncthreads();
  const float4* mr4 = (const float4*)myrow;
#pragma unroll
  for (int jj = 0; jj < 2; ++jj) {
    int j = t + jj*256;
    const float4* row4 = (const float4*)&normed[(size_t)j*DIMX];
    float s = 0.f;
#pragma unroll 8
    for (int c = 0; c < 64; ++c) {
      float4 a = mr4[c], b = row4[c];
      s += a.x*b.x + a.y*b.y + a.z*b.z + a.w*b.w;
    }
    sims[j] = s;  // TEMPERATURE = 1
  }
  __syncthreads();
  // per-wave top-17 of 128 values (ties -> lower index, matching lax.top_k)
  float va = sims[w*128 + l],  vb = sims[w*128 + 64 + l];
  int   ia = w*128 + l,        ib = w*128 + 64 + l;
  for (int it = 0; it < KNN; ++it) {
    float mv; int mi;
    if (vb > va) { mv = vb; mi = ib; } else { mv = va; mi = ia; }  // tie -> lower idx (a)
#pragma unroll
    for (int off = 1; off < 64; off <<= 1) {
      float ov = __shfl_xor(mv, off);
      int   oi = __shfl_xor(mi, off);
      if (ov > mv || (ov == mv && oi < mi)) { mv = ov; mi = oi; }
    }
    if (l == 0) { candv[w][it] = mv; candi[w][it] = mi; }
    if (mi == ia) va = -INFINITY;
    if (mi == ib) vb = -INFINITY;
  }
  __syncthreads();
  if (w == 0) {
    const float* cv = &candv[0][0];
    const int*   ci = &candi[0][0];
    float v1 = cv[l];                       int i1 = ci[l];
    float v2 = (l < 4) ? cv[64+l] : -INFINITY;
    int   i2 = (l < 4) ? ci[64+l] : 0x7fffffff;
    for (int it = 0; it < KNN; ++it) {
      float mv; int mi;
      if (v2 > v1 || (v2 == v1 && i2 < i1)) { mv = v2; mi = i2; }
      else                                  { mv = v1; mi = i1; }
#pragma unroll
      for (int off = 1; off < 64; off <<= 1) {
        float ov = __shfl_xor(mv, off);
        int   oi = __shfl_xor(mi, off);
        if (ov > mv || (ov == mv && oi < mi)) { mv = ov; mi = oi; }
      }
      if (l == 0) knn[i*32 + it] = mi;
      if (mi == i1) v1 = -INFINITY;
      if (mi == i2) v2 = -INFINITY;
    }
  }
}

// ---------------- prep: cast x->bf16; transpose-cast W_qkv, W_out to [N][K] bf16 ---------------
__global__ void prep_kernel(const float* __restrict__ x, const float* __restrict__ Wq,
                            const float* __restrict__ Wo, ushort_t* __restrict__ xbf,
                            ushort_t* __restrict__ wqT, ushort_t* __restrict__ woT) {
  int bid = blockIdx.x, t = threadIdx.x;
  if (bid < 2048) {                       // x: 16384*256 = 4.19M elems, 8 per thread
    size_t base = ((size_t)bid*256 + t)*8;
    float4 f0 = *(const float4*)&x[base];
    float4 f1 = *(const float4*)&x[base+4];
    uint4 o;
    o.x = (uint)f2bf(f0.x) | ((uint)f2bf(f0.y) << 16);
    o.y = (uint)f2bf(f0.z) | ((uint)f2bf(f0.w) << 16);
    o.z = (uint)f2bf(f1.x) | ((uint)f2bf(f1.y) << 16);
    o.w = (uint)f2bf(f1.z) | ((uint)f2bf(f1.w) << 16);
    *(uint4*)&xbf[base] = o;
  } else if (bid < 2048 + QKV_W) {        // W_qkv [256][768] -> wqT [768][256]
    int c = bid - 2048;
    wqT[(size_t)c*DIMX + t] = f2bf(Wq[(size_t)t*QKV_W + c]);
  } else {                                // W_out [256][256] -> woT [256][256]
    int c = bid - 2048 - QKV_W;
    woT[(size_t)c*DIMX + t] = f2bf(Wo[(size_t)t*DIMX + c]);
  }
}

// ---------------- MFMA bf16 GEMM: C[M,N] = A[M,K] @ Bt[N,K]^T (+bias), 128x64 tile ------------
template<bool OUTF32>
__global__ __launch_bounds__(256, 2) void mfma_gemm(
    const ushort_t* __restrict__ A, const ushort_t* __restrict__ Bt,
    void* __restrict__ Cout, const float* __restrict__ bias, int M, int N, int K) {
  __shared__ ushort_t As[128][72];  // +8 pad: 144B rows -> 2-way (free) LDS access
  __shared__ ushort_t Bs[64][72];
  int t = threadIdx.x;
  int l = t & 63, w = t >> 6;
  int wr = w >> 1, wc = w & 1;
  int row0 = blockIdx.x * 128, col0 = blockIdx.y * 64;
  float4_t acc[4][2] = {};
  for (int k0 = 0; k0 < K; k0 += 64) {
#pragma unroll
    for (int i = 0; i < 4; ++i) {       // A tile: 128x64 bf16 = 1024 16B-chunks
      int c = t + 256*i;
      int ar = c >> 3, ac8 = (c & 7) * 8;
      *(uint4*)&As[ar][ac8] = *(const uint4*)&A[(size_t)(row0+ar)*K + k0 + ac8];
    }
#pragma unroll
    for (int i = 0; i < 2; ++i) {       // Bt tile: 64x64 = 512 chunks
      int c = t + 256*i;
      int br = c >> 3, bc8 = (c & 7) * 8;
      *(uint4*)&Bs[br][bc8] = *(const uint4*)&Bt[(size_t)(col0+br)*K + k0 + bc8];
    }
    __syncthreads();
#pragma unroll
    for (int ks = 0; ks < 2; ++ks) {
      int kk = ks*32 + (l >> 4)*8;
      short8_t a[4], b[2];
#pragma unroll
      for (int m = 0; m < 4; ++m) a[m] = *(short8_t*)&As[wr*64 + m*16 + (l & 15)][kk];
#pragma unroll
      for (int n = 0; n < 2; ++n) b[n] = *(short8_t*)&Bs[wc*32 + n*16 + (l & 15)][kk];
#pragma unroll
      for (int m = 0; m < 4; ++m)
#pragma unroll
        for (int n = 0; n < 2; ++n)
          acc[m][n] = __builtin_amdgcn_mfma_f32_16x16x32_bf16(a[m], b[n], acc[m][n], 0, 0, 0);
    }
    __syncthreads();
  }
  int crow = (l >> 4) * 4, ccol = l & 15;
#pragma unroll
  for (int m = 0; m < 4; ++m)
#pragma unroll
    for (int n = 0; n < 2; ++n) {
      int col = col0 + wc*32 + n*16 + ccol;
#pragma unroll
      for (int r = 0; r < 4; ++r) {
        int row = row0 + wr*64 + m*16 + crow + r;
        if (OUTF32) ((float*)Cout)[(size_t)row*N + col] = acc[m][n][r] + bias[col];
        else        ((ushort_t*)Cout)[(size_t)row*N + col] = f2bf(acc[m][n][r]);
      }
    }
}

// ---------------- Stage D: attention (bf16 gather) -> attn_out bf16 ---------------------------
#define NF_BLK 8
__global__ __launch_bounds__(256, 8) void attn_kernel(
    const ushort_t* __restrict__ qkv, const int* __restrict__ knn,
    ushort_t* __restrict__ attn_out) {
  int b = blockIdx.x, g = blockIdx.y, t = threadIdx.x;
  int n0 = g * NF_BLK;
  __shared__ float sc_s[KNN][HEADS];
  __shared__ uint  v_lds[KNN][DIMX/2];       // 8.5 KB
  __shared__ int idxs[KNN];
  if (t < KNN) idxs[t] = knn[b*32 + t];
  __syncthreads();

  for (int nn = 0; nn < NF_BLK; ++nn) {
    int n = n0 + nn;
    if (t < KNN*HEADS) {
      int j = t >> 3, h = t & 7;
      const uint4* qp = (const uint4*)&qkv[(size_t)(b*NFEAT + n)*QKV_W + h*DHEAD];
      const uint4* kp = (const uint4*)&qkv[(size_t)(idxs[j]*NFEAT + n)*QKV_W + 256 + h*DHEAD];
      float s = 0.f;
#pragma unroll
      for (int i = 0; i < 4; ++i) {
        uint4 qv = qp[i], kv = kp[i];
        s += bf_lo(qv.x)*bf_lo(kv.x) + bf_hi(qv.x)*bf_hi(kv.x)
           + bf_lo(qv.y)*bf_lo(kv.y) + bf_hi(qv.y)*bf_hi(kv.y)
           + bf_lo(qv.z)*bf_lo(kv.z) + bf_hi(qv.z)*bf_hi(kv.z)
           + bf_lo(qv.w)*bf_lo(kv.w) + bf_hi(qv.w)*bf_hi(kv.w);
      }
      sc_s[j][h] = s * SCALE_F;
    } else {
      for (int idx = t - 136; idx < KNN*32; idx += 120) {
        int row = idx >> 5, col = idx & 31;
        uint4 wv = ((const uint4*)&qkv[(size_t)(idxs[row]*NFEAT + n)*QKV_W + 512])[col];
        ((uint4*)&v_lds[row][0])[col] = wv;
      }
    }
    __syncthreads();
    if (t < HEADS) {        // normalize once per head
      float m = -INFINITY;
#pragma unroll
      for (int j = 0; j < KNN; ++j) m = fmaxf(m, sc_s[j][t]);
      float sum = 0.f;
      float e[KNN];
#pragma unroll
      for (int j = 0; j < KNN; ++j) { e[j] = __expf(sc_s[j][t] - m); sum += e[j]; }
      float inv = 1.0f / sum;
#pragma unroll
      for (int j = 0; j < KNN; ++j) sc_s[j][t] = e[j] * inv;
    }
    __syncthreads();
    {   // PV: thread t owns output dim t
      int h = t >> 5;
      int word = t >> 1;
      bool hi = (t & 1);
      float acc = 0.f;
#pragma unroll
      for (int j = 0; j < KNN; ++j) {
        uint wv = v_lds[j][word];
        float v = hi ? bf_hi(wv) : bf_lo(wv);
        acc += sc_s[j][h] * v;
      }
      attn_out[(size_t)(b*NFEAT + n)*DIMX + t] = f2bf(acc);
    }
    __syncthreads();
  }
}

extern "C" void kernel_launch(void* const* d_in, const int* in_sizes, int n_in,
                              void* d_out, int out_size, void* d_ws, size_t ws_size,
                              hipStream_t stream) {
  const float* x      = (const float*)d_in[0];
  const float* W_qkv  = (const float*)d_in[1];
  const float* W_out  = (const float*)d_in[2];
  const float* b_out  = (const float*)d_in[3];
  const float* W_repr = (const float*)d_in[4];
  const float* b_repr = (const float*)d_in[5];
  float* out = (float*)d_out;

  ushort_t* qkv      = (ushort_t*)d_ws;                        // 16384*768 bf16
  ushort_t* xbf      = qkv + (size_t)16384*QKV_W;              // 16384*256
  ushort_t* wqT      = xbf + (size_t)16384*DIMX;               // 768*256
  ushort_t* woT      = wqT + (size_t)QKV_W*DIMX;               // 256*256
  ushort_t* attn_out = woT + (size_t)DIMX*DIMX;                // 16384*256
  float*    normed   = (float*)(attn_out + (size_t)16384*DIMX);
  int*      knn      = (int*)(normed + (size_t)BATCH*DIMX);

  repr_kernel<<<BATCH, 256, 0, stream>>>(x, W_repr, b_repr, normed);
  simtopk_kernel<<<BATCH, 256, 0, stream>>>(normed, knn);
  prep_kernel<<<2048 + QKV_W + DIMX, 256, 0, stream>>>(x, W_qkv, W_out, xbf, wqT, woT);
  mfma_gemm<false><<<dim3(16384/128, QKV_W/64), 256, 0, stream>>>(
      xbf, wqT, qkv, nullptr, 16384, QKV_W, DIMX);
  attn_kernel<<<dim3(BATCH, NFEAT/NF_BLK), 256, 0, stream>>>(qkv, knn, attn_out);
  mfma_gemm<true><<<dim3(16384/128, DIMX/64), 256, 0, stream>>>(
      attn_out, woT, out, b_out, 16384, DIMX, DIMX);
}

// Round 7
// 123.698 us; speedup vs baseline: 1.1441x; 1.1441x over previous
//
#include <hip/hip_runtime.h>
#include <math.h>

#define DIMX 256
#define NFEAT 32
#define BATCH 512
#define HEADS 8
#define DHEAD 32
#define KNN 17
#define QKV_W 768
#define SCALE_F 0.17677669529663687f

typedef unsigned int uint;
typedef unsigned short ushort_t;
typedef __attribute__((ext_vector_type(8))) short short8_t;   // 8 bf16 (4 VGPRs)
typedef __attribute__((ext_vector_type(4))) float float4_t;   // MFMA acc

__device__ inline float bf_lo(uint u) { return __uint_as_float(u << 16); }
__device__ inline float bf_hi(uint u) { return __uint_as_float(u & 0xffff0000u); }
__device__ inline ushort_t f2bf(float f) {
  uint u = __float_as_uint(f);
  return (ushort_t)((u + 0x7fffu + ((u >> 16) & 1u)) >> 16);
}

// ---------------- Stage A: reprs = mean(x,axis=1) @ W_repr + b_repr; normalize ----------------
__global__ void repr_kernel(const float* __restrict__ x, const float* __restrict__ W_repr,
                            const float* __restrict__ b_repr, float* __restrict__ normed) {
  int b = blockIdx.x, t = threadIdx.x;
  __shared__ float mean_s[DIMX];
  __shared__ float red[DIMX];
  float s = 0.f;
#pragma unroll
  for (int n = 0; n < NFEAT; ++n) s += x[(size_t)(b*NFEAT+n)*DIMX + t];
  mean_s[t] = s * (1.0f/NFEAT);
  __syncthreads();
  float acc = b_repr[t];
  for (int d = 0; d < DIMX; ++d) acc += mean_s[d] * W_repr[d*DIMX + t];
  red[t] = acc*acc;
  __syncthreads();
  for (int off = 128; off > 0; off >>= 1) {
    if (t < off) red[t] += red[t+off];
    __syncthreads();
  }
  normed[b*DIMX + t] = acc / sqrtf(red[0]);
}

// ---------------- Stage B1: sims = normed @ normed^T (f32, 32x32 tiles) -----------------------
__global__ __launch_bounds__(256, 4) void sim_gemm(const float* __restrict__ normed,
                                                   float* __restrict__ sims) {
  __shared__ float As[32][68];
  __shared__ float Bs[32][68];
  int t = threadIdx.x;
  int i0 = blockIdx.x * 32, j0 = blockIdx.y * 32;
  int tx = t & 15, ty = t >> 4;
  float acc00 = 0.f, acc01 = 0.f, acc10 = 0.f, acc11 = 0.f;
  for (int k0 = 0; k0 < DIMX; k0 += 64) {
#pragma unroll
    for (int c = t; c < 512; c += 256) {
      int r = c >> 4, cc = (c & 15) * 4;
      *(float4*)&As[r][cc] = *(const float4*)&normed[(size_t)(i0 + r)*DIMX + k0 + cc];
      *(float4*)&Bs[r][cc] = *(const float4*)&normed[(size_t)(j0 + r)*DIMX + k0 + cc];
    }
    __syncthreads();
#pragma unroll 16
    for (int kk = 0; kk < 64; ++kk) {
      float a0 = As[ty*2][kk],   a1 = As[ty*2+1][kk];
      float b0 = Bs[tx*2][kk],   b1 = Bs[tx*2+1][kk];
      acc00 += a0*b0; acc01 += a0*b1; acc10 += a1*b0; acc11 += a1*b1;
    }
    __syncthreads();
  }
  sims[(size_t)(i0+ty*2  )*BATCH + j0+tx*2  ] = acc00;
  sims[(size_t)(i0+ty*2  )*BATCH + j0+tx*2+1] = acc01;
  sims[(size_t)(i0+ty*2+1)*BATCH + j0+tx*2  ] = acc10;
  sims[(size_t)(i0+ty*2+1)*BATCH + j0+tx*2+1] = acc11;
}

// ---------------- Stage B2: top-17 via rank selection (exact lax.top_k order) ------------------
// rank(j) = #{m : v_m > v_j or (v_m == v_j and m < j)}; j in top-17 iff rank < 17, and rank is
// its exact position in lax.top_k output (stable descending sort). Branch-free, no shuffles.
__global__ __launch_bounds__(256, 8) void topk_rank(const float* __restrict__ sims,
                                                    int* __restrict__ knn) {
  int i = blockIdx.x, t = threadIdx.x;
  __shared__ float row[BATCH];
  row[t]       = sims[(size_t)i*BATCH + t];
  row[t + 256] = sims[(size_t)i*BATCH + t + 256];
  __syncthreads();
  float v1 = row[t], v2 = row[t + 256];
  int i1 = t, i2 = t + 256;
  int r1 = 0, r2 = 0;
  const float4* r4 = (const float4*)row;
#pragma unroll 8
  for (int c = 0; c < BATCH/4; ++c) {
    float4 q = r4[c];            // LDS broadcast (same addr all lanes)
    int base = c * 4;
    r1 += (q.x > v1 || (q.x == v1 && base+0 < i1));
    r1 += (q.y > v1 || (q.y == v1 && base+1 < i1));
    r1 += (q.z > v1 || (q.z == v1 && base+2 < i1));
    r1 += (q.w > v1 || (q.w == v1 && base+3 < i1));
    r2 += (q.x > v2 || (q.x == v2 && base+0 < i2));
    r2 += (q.y > v2 || (q.y == v2 && base+1 < i2));
    r2 += (q.z > v2 || (q.z == v2 && base+2 < i2));
    r2 += (q.w > v2 || (q.w == v2 && base+3 < i2));
  }
  if (r1 < KNN) knn[i*32 + r1] = i1;
  if (r2 < KNN) knn[i*32 + r2] = i2;
}

// ---------------- prep: cast x->bf16; transpose-cast W_qkv, W_out to [N][K] bf16 ---------------
__global__ void prep_kernel(const float* __restrict__ x, const float* __restrict__ Wq,
                            const float* __restrict__ Wo, ushort_t* __restrict__ xbf,
                            ushort_t* __restrict__ wqT, ushort_t* __restrict__ woT) {
  int bid = blockIdx.x, t = threadIdx.x;
  if (bid < 2048) {                       // x: 16384*256 = 4.19M elems, 8 per thread
    size_t base = ((size_t)bid*256 + t)*8;
    float4 f0 = *(const float4*)&x[base];
    float4 f1 = *(const float4*)&x[base+4];
    uint4 o;
    o.x = (uint)f2bf(f0.x) | ((uint)f2bf(f0.y) << 16);
    o.y = (uint)f2bf(f0.z) | ((uint)f2bf(f0.w) << 16);
    o.z = (uint)f2bf(f1.x) | ((uint)f2bf(f1.y) << 16);
    o.w = (uint)f2bf(f1.z) | ((uint)f2bf(f1.w) << 16);
    *(uint4*)&xbf[base] = o;
  } else if (bid < 2048 + QKV_W) {        // W_qkv [256][768] -> wqT [768][256]
    int c = bid - 2048;
    wqT[(size_t)c*DIMX + t] = f2bf(Wq[(size_t)t*QKV_W + c]);
  } else {                                // W_out [256][256] -> woT [256][256]
    int c = bid - 2048 - QKV_W;
    woT[(size_t)c*DIMX + t] = f2bf(Wo[(size_t)t*DIMX + c]);
  }
}

// ---------------- MFMA bf16 GEMM: C[M,N] = A[M,K] @ Bt[N,K]^T (+bias), 128x64 tile ------------
template<bool OUTF32>
__global__ __launch_bounds__(256, 2) void mfma_gemm(
    const ushort_t* __restrict__ A, const ushort_t* __restrict__ Bt,
    void* __restrict__ Cout, const float* __restrict__ bias, int M, int N, int K) {
  __shared__ ushort_t As[128][72];  // +8 pad: 144B rows -> 2-way (free) LDS access
  __shared__ ushort_t Bs[64][72];
  int t = threadIdx.x;
  int l = t & 63, w = t >> 6;
  int wr = w >> 1, wc = w & 1;
  int row0 = blockIdx.x * 128, col0 = blockIdx.y * 64;
  float4_t acc[4][2] = {};
  for (int k0 = 0; k0 < K; k0 += 64) {
#pragma unroll
    for (int i = 0; i < 4; ++i) {       // A tile: 128x64 bf16 = 1024 16B-chunks
      int c = t + 256*i;
      int ar = c >> 3, ac8 = (c & 7) * 8;
      *(uint4*)&As[ar][ac8] = *(const uint4*)&A[(size_t)(row0+ar)*K + k0 + ac8];
    }
#pragma unroll
    for (int i = 0; i < 2; ++i) {       // Bt tile: 64x64 = 512 chunks
      int c = t + 256*i;
      int br = c >> 3, bc8 = (c & 7) * 8;
      *(uint4*)&Bs[br][bc8] = *(const uint4*)&Bt[(size_t)(col0+br)*K + k0 + bc8];
    }
    __syncthreads();
#pragma unroll
    for (int ks = 0; ks < 2; ++ks) {
      int kk = ks*32 + (l >> 4)*8;
      short8_t a[4], b[2];
#pragma unroll
      for (int m = 0; m < 4; ++m) a[m] = *(short8_t*)&As[wr*64 + m*16 + (l & 15)][kk];
#pragma unroll
      for (int n = 0; n < 2; ++n) b[n] = *(short8_t*)&Bs[wc*32 + n*16 + (l & 15)][kk];
#pragma unroll
      for (int m = 0; m < 4; ++m)
#pragma unroll
        for (int n = 0; n < 2; ++n)
          acc[m][n] = __builtin_amdgcn_mfma_f32_16x16x32_bf16(a[m], b[n], acc[m][n], 0, 0, 0);
    }
    __syncthreads();
  }
  int crow = (l >> 4) * 4, ccol = l & 15;
#pragma unroll
  for (int m = 0; m < 4; ++m)
#pragma unroll
    for (int n = 0; n < 2; ++n) {
      int col = col0 + wc*32 + n*16 + ccol;
#pragma unroll
      for (int r = 0; r < 4; ++r) {
        int row = row0 + wr*64 + m*16 + crow + r;
        if (OUTF32) ((float*)Cout)[(size_t)row*N + col] = acc[m][n][r] + bias[col];
        else        ((ushort_t*)Cout)[(size_t)row*N + col] = f2bf(acc[m][n][r]);
      }
    }
}

// ---------------- Stage D: attention (bf16 gather) -> attn_out bf16 ---------------------------
#define NF_BLK 8
__global__ __launch_bounds__(256, 8) void attn_kernel(
    const ushort_t* __restrict__ qkv, const int* __restrict__ knn,
    ushort_t* __restrict__ attn_out) {
  int b = blockIdx.x, g = blockIdx.y, t = threadIdx.x;
  int n0 = g * NF_BLK;
  __shared__ float sc_s[KNN][HEADS];
  __shared__ uint  v_lds[KNN][DIMX/2];       // 8.5 KB
  __shared__ int idxs[KNN];
  if (t < KNN) idxs[t] = knn[b*32 + t];
  __syncthreads();

  for (int nn = 0; nn < NF_BLK; ++nn) {
    int n = n0 + nn;
    if (t < KNN*HEADS) {
      int j = t >> 3, h = t & 7;
      const uint4* qp = (const uint4*)&qkv[(size_t)(b*NFEAT + n)*QKV_W + h*DHEAD];
      const uint4* kp = (const uint4*)&qkv[(size_t)(idxs[j]*NFEAT + n)*QKV_W + 256 + h*DHEAD];
      float s = 0.f;
#pragma unroll
      for (int i = 0; i < 4; ++i) {
        uint4 qv = qp[i], kv = kp[i];
        s += bf_lo(qv.x)*bf_lo(kv.x) + bf_hi(qv.x)*bf_hi(kv.x)
           + bf_lo(qv.y)*bf_lo(kv.y) + bf_hi(qv.y)*bf_hi(kv.y)
           + bf_lo(qv.z)*bf_lo(kv.z) + bf_hi(qv.z)*bf_hi(kv.z)
           + bf_lo(qv.w)*bf_lo(kv.w) + bf_hi(qv.w)*bf_hi(kv.w);
      }
      sc_s[j][h] = s * SCALE_F;
    } else {
      for (int idx = t - 136; idx < KNN*32; idx += 120) {
        int row = idx >> 5, col = idx & 31;
        uint4 wv = ((const uint4*)&qkv[(size_t)(idxs[row]*NFEAT + n)*QKV_W + 512])[col];
        ((uint4*)&v_lds[row][0])[col] = wv;
      }
    }
    __syncthreads();
    if (t < HEADS) {        // normalize once per head
      float m = -INFINITY;
#pragma unroll
      for (int j = 0; j < KNN; ++j) m = fmaxf(m, sc_s[j][t]);
      float sum = 0.f;
      float e[KNN];
#pragma unroll
      for (int j = 0; j < KNN; ++j) { e[j] = __expf(sc_s[j][t] - m); sum += e[j]; }
      float inv = 1.0f / sum;
#pragma unroll
      for (int j = 0; j < KNN; ++j) sc_s[j][t] = e[j] * inv;
    }
    __syncthreads();
    {   // PV: thread t owns output dim t
      int h = t >> 5;
      int word = t >> 1;
      bool hi = (t & 1);
      float acc = 0.f;
#pragma unroll
      for (int j = 0; j < KNN; ++j) {
        uint wv = v_lds[j][word];
        float v = hi ? bf_hi(wv) : bf_lo(wv);
        acc += sc_s[j][h] * v;
      }
      attn_out[(size_t)(b*NFEAT + n)*DIMX + t] = f2bf(acc);
    }
    __syncthreads();
  }
}

extern "C" void kernel_launch(void* const* d_in, const int* in_sizes, int n_in,
                              void* d_out, int out_size, void* d_ws, size_t ws_size,
                              hipStream_t stream) {
  const float* x      = (const float*)d_in[0];
  const float* W_qkv  = (const float*)d_in[1];
  const float* W_out  = (const float*)d_in[2];
  const float* b_out  = (const float*)d_in[3];
  const float* W_repr = (const float*)d_in[4];
  const float* b_repr = (const float*)d_in[5];
  float* out = (float*)d_out;

  ushort_t* qkv      = (ushort_t*)d_ws;                        // 16384*768 bf16
  ushort_t* xbf      = qkv + (size_t)16384*QKV_W;              // 16384*256
  ushort_t* wqT      = xbf + (size_t)16384*DIMX;               // 768*256
  ushort_t* woT      = wqT + (size_t)QKV_W*DIMX;               // 256*256
  ushort_t* attn_out = woT + (size_t)DIMX*DIMX;                // 16384*256
  float*    normed   = (float*)(attn_out + (size_t)16384*DIMX);
  float*    sims     = normed + (size_t)BATCH*DIMX;            // 512*512 f32 = 1 MB
  int*      knn      = (int*)(sims + (size_t)BATCH*BATCH);

  repr_kernel<<<BATCH, 256, 0, stream>>>(x, W_repr, b_repr, normed);
  sim_gemm<<<dim3(BATCH/32, BATCH/32), 256, 0, stream>>>(normed, sims);
  topk_rank<<<BATCH, 256, 0, stream>>>(sims, knn);
  prep_kernel<<<2048 + QKV_W + DIMX, 256, 0, stream>>>(x, W_qkv, W_out, xbf, wqT, woT);
  mfma_gemm<false><<<dim3(16384/128, QKV_W/64), 256, 0, stream>>>(
      xbf, wqT, qkv, nullptr, 16384, QKV_W, DIMX);
  attn_kernel<<<dim3(BATCH, NFEAT/NF_BLK), 256, 0, stream>>>(qkv, knn, attn_out);
  mfma_gemm<true><<<dim3(16384/128, DIMX/64), 256, 0, stream>>>(
      attn_out, woT, out, b_out, 16384, DIMX, DIMX);
}